// Round 4
// baseline (2807.670 us; speedup 1.0000x reference)
//
#include <hip/hip_runtime.h>
#include <hip/hip_cooperative_groups.h>
#include <stdint.h>

namespace cg = cooperative_groups;

#define NROWS 32768
#define DDIM  512
#define KDIM  512

__device__ __forceinline__ float b2f(unsigned short u) {
  return __uint_as_float(((unsigned int)u) << 16);
}
__device__ __forceinline__ unsigned short f2bf(float f) {
  unsigned int u = __float_as_uint(f);
  u += 0x7FFFu + ((u >> 16) & 1u);   // round-to-nearest-even
  return (unsigned short)(u >> 16);
}

typedef __attribute__((ext_vector_type(8))) short bf16x8;
typedef __attribute__((ext_vector_type(4))) float f32x4;

// ---------------------------------------------------------------------------
// prep: row inverse-norms for z1/z2 (rows 0..65535) and normalized bf16 weight
// ---------------------------------------------------------------------------
__global__ __launch_bounds__(256) void prep_kernel(
    const float* __restrict__ z1, const float* __restrict__ z2,
    const float* __restrict__ w, float* __restrict__ rnorm,
    unsigned short* __restrict__ wnb) {
  const int tid = threadIdx.x;
  const int wv = tid >> 6, ln = tid & 63;
  const int row = blockIdx.x * 4 + wv;   // 0..66047
  const float* src;
  if (row < NROWS)        src = z1 + (size_t)row * DDIM;
  else if (row < 2*NROWS) src = z2 + (size_t)(row - NROWS) * DDIM;
  else                    src = w  + (size_t)(row - 2*NROWS) * DDIM;
  float4 v0 = ((const float4*)src)[ln*2];
  float4 v1 = ((const float4*)src)[ln*2+1];
  float ss = v0.x*v0.x + v0.y*v0.y + v0.z*v0.z + v0.w*v0.w
           + v1.x*v1.x + v1.y*v1.y + v1.z*v1.z + v1.w*v1.w;
  #pragma unroll
  for (int off = 1; off < 64; off <<= 1) ss += __shfl_xor(ss, off);
  float rn = 1.0f / fmaxf(sqrtf(ss), 1e-12f);
  if (row < 2*NROWS) {
    if (ln == 0) rnorm[row] = rn;
  } else {
    int r = row - 2*NROWS;
    ushort4 o0 = make_ushort4(f2bf(v0.x*rn), f2bf(v0.y*rn), f2bf(v0.z*rn), f2bf(v0.w*rn));
    ushort4 o1 = make_ushort4(f2bf(v1.x*rn), f2bf(v1.y*rn), f2bf(v1.z*rn), f2bf(v1.w*rn));
    ushort4* dst = (ushort4*)(wnb + (size_t)r*DDIM + ln*8);
    dst[0] = o0; dst[1] = o1;
  }
}

// ---------------------------------------------------------------------------
// initvecs: zero the 20 column-sum buffers (T[20][2*512]) and the output
// ---------------------------------------------------------------------------
__global__ void initvecs_kernel(float* __restrict__ T, float* __restrict__ out) {
  int i = blockIdx.x * 256 + threadIdx.x;
  if (i < 20 * 1024) T[i] = 0.f;
  if (i == 0) out[0] = 0.f;
}

// ---------------------------------------------------------------------------
// gemm: zc[r,c] = sum_d (z[r,d]*rnorm[r]) * wnb[c,d]   (bf16 MFMA, A*B^T)
// 128x128 tile, BK=32, 4 waves each 64x64 via 4x4 of 16x16x32 MFMAs
// ---------------------------------------------------------------------------
__global__ __launch_bounds__(256) void gemm_kernel(
    const float* __restrict__ z1, const float* __restrict__ z2,
    const float* __restrict__ rnorm, const unsigned short* __restrict__ wnb,
    unsigned short* __restrict__ zc) {
  constexpr int LDT = 40;   // padded LDS stride (elements): 80B rows, 16B aligned
  __shared__ unsigned short As[128 * LDT];
  __shared__ unsigned short Bs[128 * LDT];
  const int tid = threadIdx.x;
  const int colBase = blockIdx.x * 128;
  const int rowBase = blockIdx.y * 128;
  const float* Aptr = (rowBase < NROWS) ? (z1 + (size_t)rowBase * DDIM)
                                        : (z2 + (size_t)(rowBase - NROWS) * DDIM);
  const int wv = tid >> 6, ln = tid & 63;
  const int wm = wv & 1, wn = wv >> 1;
  const int lrow = ln & 15, quad = ln >> 4;

  f32x4 acc[4][4] = {};

  for (int k0 = 0; k0 < DDIM; k0 += 32) {
    // stage A (fp32 -> normalized bf16): 128 rows x 32 k
    #pragma unroll
    for (int i = 0; i < 4; i++) {
      int idx = i * 256 + tid;            // 0..1023
      int r = idx >> 3;                   // 0..127
      int kk = (idx & 7) * 4;             // 0..28
      float4 v = *(const float4*)(Aptr + (size_t)r * DDIM + k0 + kk);
      float rn = rnorm[rowBase + r];
      ushort4 o = make_ushort4(f2bf(v.x*rn), f2bf(v.y*rn), f2bf(v.z*rn), f2bf(v.w*rn));
      *(ushort4*)(&As[r * LDT + kk]) = o;
    }
    // stage B (bf16 weight): 128 rows x 32 k
    #pragma unroll
    for (int i = 0; i < 2; i++) {
      int idx = i * 256 + tid;            // 0..511
      int r = idx >> 2;                   // 0..127
      int kk = (idx & 3) * 8;             // 0..24
      float4 v = *(const float4*)(wnb + (size_t)(colBase + r) * DDIM + k0 + kk);
      *(float4*)(&Bs[r * LDT + kk]) = v;
    }
    __syncthreads();
    bf16x8 af[4], bfr[4];
    #pragma unroll
    for (int mi = 0; mi < 4; mi++)
      af[mi] = *(const bf16x8*)(&As[(64*wm + 16*mi + lrow) * LDT + quad*8]);
    #pragma unroll
    for (int ni = 0; ni < 4; ni++)
      bfr[ni] = *(const bf16x8*)(&Bs[(64*wn + 16*ni + lrow) * LDT + quad*8]);
    #pragma unroll
    for (int mi = 0; mi < 4; mi++)
      #pragma unroll
      for (int ni = 0; ni < 4; ni++)
        acc[mi][ni] = __builtin_amdgcn_mfma_f32_16x16x32_bf16(
            af[mi], bfr[ni], acc[mi][ni], 0, 0, 0);
    __syncthreads();
  }
  // epilogue: C/D layout col=lane&15, row=(lane>>4)*4+reg
  #pragma unroll
  for (int mi = 0; mi < 4; mi++)
    #pragma unroll
    for (int ni = 0; ni < 4; ni++)
      #pragma unroll
      for (int r = 0; r < 4; r++) {
        size_t grow = (size_t)rowBase + 64*wm + 16*mi + quad*4 + r;
        int gcol = colBase + 64*wn + 16*ni + lrow;
        zc[grow * KDIM + gcol] = f2bf(acc[mi][ni][r]);
      }
}

// ---------------------------------------------------------------------------
// sink_coop: all 20 sinkhorn iterations in one cooperative kernel.
// e = exp(20*zc) lives in VGPRs packed as bf16 pairs: 16 rows x 8 cols/lane
// = 64 uint VGPRs data. 256 blocks x 1024 thr = 1 block/CU (co-resident),
// __launch_bounds__(1024,4) -> 128-VGPR cap, no spill (~100 used).
// iter 0:   T0[k]  = sum_rows e
// iter t>0: a_k = 1/(K*T[t-1][k]); per row s = sum_k e*a; b = 1/(B*s);
//           T[t][k] += sum_rows e[k]*b
// blocks 0..127 -> matrix 0 (zc1), 128..255 -> matrix 1 (zc2)
// ---------------------------------------------------------------------------
__global__ __launch_bounds__(1024, 4) void sink_coop(
    const unsigned short* __restrict__ zc, float* __restrict__ T) {
  __shared__ float red[16 * 512];
  const int tid = threadIdx.x;
  const int wv = tid >> 6, ln = tid & 63;
  const int gw = blockIdx.x * 16 + wv;      // 0..4095
  const size_t row0 = (size_t)gw * 16;
  const int mat = blockIdx.x >> 7;          // 0 or 1 (block-uniform)

  unsigned int pk[16][4];                    // e packed bf16 pairs
  {
    const unsigned short* base = zc + row0 * 512 + ln * 8;
    #pragma unroll
    for (int r = 0; r < 16; r++) {
      const ushort4* p = (const ushort4*)(base + (size_t)r * 512);
      ushort4 u0 = p[0], u1 = p[1];
      float e0 = __expf(b2f(u0.x)*20.f), e1 = __expf(b2f(u0.y)*20.f);
      float e2 = __expf(b2f(u0.z)*20.f), e3 = __expf(b2f(u0.w)*20.f);
      float e4 = __expf(b2f(u1.x)*20.f), e5 = __expf(b2f(u1.y)*20.f);
      float e6 = __expf(b2f(u1.z)*20.f), e7 = __expf(b2f(u1.w)*20.f);
      pk[r][0] = ((unsigned int)f2bf(e1) << 16) | f2bf(e0);
      pk[r][1] = ((unsigned int)f2bf(e3) << 16) | f2bf(e2);
      pk[r][2] = ((unsigned int)f2bf(e5) << 16) | f2bf(e4);
      pk[r][3] = ((unsigned int)f2bf(e7) << 16) | f2bf(e6);
    }
  }

  cg::grid_group grid = cg::this_grid();

  for (int t = 0; t < 20; t++) {
    float acc[8] = {0,0,0,0,0,0,0,0};
    if (t == 0) {
      #pragma unroll
      for (int r = 0; r < 16; r++) {
        #pragma unroll
        for (int i = 0; i < 4; i++) {
          acc[2*i]   += __uint_as_float(pk[r][i] << 16);
          acc[2*i+1] += __uint_as_float(pk[r][i] & 0xFFFF0000u);
        }
      }
    } else {
      float a[8];
      const float* Tp = T + (size_t)(t - 1) * 1024 + mat * 512 + ln * 8;
      #pragma unroll
      for (int j = 0; j < 8; j++) {
        float u = __hip_atomic_load(Tp + j, __ATOMIC_RELAXED, __HIP_MEMORY_SCOPE_AGENT);
        a[j] = 1.0f / (512.0f * u);
      }
      #pragma unroll
      for (int r = 0; r < 16; r++) {
        float ev[8];
        #pragma unroll
        for (int i = 0; i < 4; i++) {
          ev[2*i]   = __uint_as_float(pk[r][i] << 16);
          ev[2*i+1] = __uint_as_float(pk[r][i] & 0xFFFF0000u);
        }
        float part = ev[0]*a[0]+ev[1]*a[1]+ev[2]*a[2]+ev[3]*a[3]
                   + ev[4]*a[4]+ev[5]*a[5]+ev[6]*a[6]+ev[7]*a[7];
        #pragma unroll
        for (int off = 1; off < 64; off <<= 1) part += __shfl_xor(part, off);
        float b = 1.0f / (32768.0f * part);
        #pragma unroll
        for (int j = 0; j < 8; j++) acc[j] += ev[j] * b;
      }
    }
    // block reduce: bank-swizzled scalar stores (<=2-way, free), then 512-wide sum
    #pragma unroll
    for (int j = 0; j < 8; j++) {
      int pos = ln * 8 + ((j + (ln >> 2)) & 7);
      red[wv * 512 + pos] = acc[j];
    }
    __syncthreads();
    if (tid < 512) {
      int pos = (tid & ~7) | (((tid & 7) + (tid >> 5)) & 7);
      float s = 0.f;
      #pragma unroll
      for (int w = 0; w < 16; w++) s += red[w * 512 + pos];
      unsafeAtomicAdd(&T[(size_t)t * 1024 + mat * 512 + tid], s);
    }
    __threadfence();
    grid.sync();
  }
}

// ---------------------------------------------------------------------------
// loss: a20 = 1/(K*T19); per row: q = M*a/s (s = sum_k M*a);
// logp = z/tau - logsumexp(z/tau);  out -= (sum_k q1*logp2 + q2*logp1)/N
// 16 waves/block, 4 rows/wave, 512 blocks
// ---------------------------------------------------------------------------
__global__ __launch_bounds__(1024) void loss_kernel(
    const unsigned short* __restrict__ zc,
    const float* __restrict__ T19, float* __restrict__ out) {
  const int tid = threadIdx.x;
  const int wv = tid >> 6, ln = tid & 63;
  const int gw = blockIdx.x * 16 + wv;      // 0..8191
  const size_t row0 = (size_t)gw * 4;
  float a1[8], a2[8];
  #pragma unroll
  for (int j = 0; j < 8; j++) {
    a1[j] = 1.0f / (512.0f * T19[ln*8 + j]);
    a2[j] = 1.0f / (512.0f * T19[512 + ln*8 + j]);
  }
  const float invTau = 1.0f / 0.3f;
  float part = 0.f;
  for (int r = 0; r < 4; r++) {
    size_t b = row0 + r;
    const ushort4* p1 = (const ushort4*)(zc + b * 512 + ln * 8);
    const ushort4* p2 = (const ushort4*)(zc + (b + NROWS) * 512 + ln * 8);
    ushort4 u10 = p1[0], u11 = p1[1], u20 = p2[0], u21 = p2[1];
    float zf1[8], zf2[8];
    zf1[0]=b2f(u10.x); zf1[1]=b2f(u10.y); zf1[2]=b2f(u10.z); zf1[3]=b2f(u10.w);
    zf1[4]=b2f(u11.x); zf1[5]=b2f(u11.y); zf1[6]=b2f(u11.z); zf1[7]=b2f(u11.w);
    zf2[0]=b2f(u20.x); zf2[1]=b2f(u20.y); zf2[2]=b2f(u20.z); zf2[3]=b2f(u20.w);
    zf2[4]=b2f(u21.x); zf2[5]=b2f(u21.y); zf2[6]=b2f(u21.z); zf2[7]=b2f(u21.w);
    float m1 = -1e30f, m2 = -1e30f;
    #pragma unroll
    for (int j = 0; j < 8; j++) { m1 = fmaxf(m1, zf1[j]); m2 = fmaxf(m2, zf2[j]); }
    #pragma unroll
    for (int off = 1; off < 64; off <<= 1) {
      m1 = fmaxf(m1, __shfl_xor(m1, off));
      m2 = fmaxf(m2, __shfl_xor(m2, off));
    }
    float se1 = 0.f, se2 = 0.f;
    #pragma unroll
    for (int j = 0; j < 8; j++) {
      se1 += __expf((zf1[j] - m1) * invTau);
      se2 += __expf((zf2[j] - m2) * invTau);
    }
    #pragma unroll
    for (int off = 1; off < 64; off <<= 1) {
      se1 += __shfl_xor(se1, off);
      se2 += __shfl_xor(se2, off);
    }
    float ls1 = m1 * invTau + __logf(se1);
    float ls2 = m2 * invTau + __logf(se2);
    float s1 = 0.f, n1 = 0.f, s2 = 0.f, n2 = 0.f;
    #pragma unroll
    for (int j = 0; j < 8; j++) {
      float e1 = __expf(zf1[j] * 20.f) * a1[j];
      s1 += e1; n1 += e1 * (zf2[j] * invTau - ls2);
      float e2 = __expf(zf2[j] * 20.f) * a2[j];
      s2 += e2; n2 += e2 * (zf1[j] * invTau - ls1);
    }
    #pragma unroll
    for (int off = 1; off < 64; off <<= 1) {
      s1 += __shfl_xor(s1, off); n1 += __shfl_xor(n1, off);
      s2 += __shfl_xor(s2, off); n2 += __shfl_xor(n2, off);
    }
    part += n1 / s1 + n2 / s2;
  }
  __shared__ float red[16];
  if (ln == 0) red[wv] = part;
  __syncthreads();
  if (tid == 0) {
    float s = 0.f;
    #pragma unroll
    for (int w = 0; w < 16; w++) s += red[w];
    unsafeAtomicAdd(out, -s * (1.0f / 32768.0f));
  }
}

// ---------------------------------------------------------------------------
extern "C" void kernel_launch(void* const* d_in, const int* in_sizes, int n_in,
                              void* d_out, int out_size, void* d_ws, size_t ws_size,
                              hipStream_t stream) {
  (void)in_sizes; (void)n_in; (void)out_size; (void)ws_size;
  const float* z1 = (const float*)d_in[0];
  const float* z2 = (const float*)d_in[1];
  const float* w  = (const float*)d_in[2];
  float* out = (float*)d_out;
  char* ws = (char*)d_ws;
  // workspace layout
  unsigned short* zc    = (unsigned short*)ws;                         // 67,108,864 B
  float*          rnorm = (float*)(ws + (size_t)67108864);             //    262,144 B
  unsigned short* wnb   = (unsigned short*)(ws + (size_t)67371008);    //    524,288 B
  float*          T     = (float*)(ws + (size_t)67895296);             //     81,920 B

  hipLaunchKernelGGL(prep_kernel, dim3(16512), dim3(256), 0, stream, z1, z2, w, rnorm, wnb);
  hipLaunchKernelGGL(initvecs_kernel, dim3(80), dim3(256), 0, stream, T, out);
  hipLaunchKernelGGL(gemm_kernel, dim3(4, 512), dim3(256), 0, stream, z1, z2, rnorm, wnb, zc);
  {
    const unsigned short* zc_c = zc;
    float* T_p = T;
    void* args[] = { (void*)&zc_c, (void*)&T_p };
    hipLaunchCooperativeKernel((void*)sink_coop, dim3(256), dim3(1024), args, 0, stream);
  }
  hipLaunchKernelGGL(loss_kernel, dim3(512), dim3(1024), 0, stream, zc, T + 19*1024, out);
}

// Round 5
// 1588.452 us; speedup vs baseline: 1.7676x; 1.7676x over previous
//
#include <hip/hip_runtime.h>
#include <stdint.h>

#define NROWS 32768
#define DDIM  512
#define KDIM  512

__device__ __forceinline__ float b2f(unsigned short u) {
  return __uint_as_float(((unsigned int)u) << 16);
}
__device__ __forceinline__ unsigned short f2bf(float f) {
  unsigned int u = __float_as_uint(f);
  u += 0x7FFFu + ((u >> 16) & 1u);   // round-to-nearest-even
  return (unsigned short)(u >> 16);
}

typedef __attribute__((ext_vector_type(8))) short bf16x8;
typedef __attribute__((ext_vector_type(4))) float f32x4;

// ---------------------------------------------------------------------------
// prep: row inverse-norms for z1/z2 (rows 0..65535) and normalized bf16 weight
// ---------------------------------------------------------------------------
__global__ __launch_bounds__(256) void prep_kernel(
    const float* __restrict__ z1, const float* __restrict__ z2,
    const float* __restrict__ w, float* __restrict__ rnorm,
    unsigned short* __restrict__ wnb) {
  const int tid = threadIdx.x;
  const int wv = tid >> 6, ln = tid & 63;
  const int row = blockIdx.x * 4 + wv;   // 0..66047
  const float* src;
  if (row < NROWS)        src = z1 + (size_t)row * DDIM;
  else if (row < 2*NROWS) src = z2 + (size_t)(row - NROWS) * DDIM;
  else                    src = w  + (size_t)(row - 2*NROWS) * DDIM;
  float4 v0 = ((const float4*)src)[ln*2];
  float4 v1 = ((const float4*)src)[ln*2+1];
  float ss = v0.x*v0.x + v0.y*v0.y + v0.z*v0.z + v0.w*v0.w
           + v1.x*v1.x + v1.y*v1.y + v1.z*v1.z + v1.w*v1.w;
  #pragma unroll
  for (int off = 1; off < 64; off <<= 1) ss += __shfl_xor(ss, off);
  float rn = 1.0f / fmaxf(sqrtf(ss), 1e-12f);
  if (row < 2*NROWS) {
    if (ln == 0) rnorm[row] = rn;
  } else {
    int r = row - 2*NROWS;
    ushort4 o0 = make_ushort4(f2bf(v0.x*rn), f2bf(v0.y*rn), f2bf(v0.z*rn), f2bf(v0.w*rn));
    ushort4 o1 = make_ushort4(f2bf(v1.x*rn), f2bf(v1.y*rn), f2bf(v1.z*rn), f2bf(v1.w*rn));
    ushort4* dst = (ushort4*)(wnb + (size_t)r*DDIM + ln*8);
    dst[0] = o0; dst[1] = o1;
  }
}

// ---------------------------------------------------------------------------
// initvecs: zero the 20 column-sum buffers (T[20][2*512]) + barrier + out
// ---------------------------------------------------------------------------
__global__ void initvecs_kernel(float* __restrict__ T, float* __restrict__ out) {
  int i = blockIdx.x * 256 + threadIdx.x;
  if (i < 20 * 1024 + 2) T[i] = 0.f;     // +2: grid-barrier {count, gen}
  if (i == 0) out[0] = 0.f;
}

// ---------------------------------------------------------------------------
// gemm: zc[r,c] = sum_d (z[r,d]*rnorm[r]) * wnb[c,d]   (bf16 MFMA, A*B^T)
// 128x128 tile, BK=32, 4 waves each 64x64 via 4x4 of 16x16x32 MFMAs
// ---------------------------------------------------------------------------
__global__ __launch_bounds__(256) void gemm_kernel(
    const float* __restrict__ z1, const float* __restrict__ z2,
    const float* __restrict__ rnorm, const unsigned short* __restrict__ wnb,
    unsigned short* __restrict__ zc) {
  constexpr int LDT = 40;   // padded LDS stride (elements): 80B rows, 16B aligned
  __shared__ unsigned short As[128 * LDT];
  __shared__ unsigned short Bs[128 * LDT];
  const int tid = threadIdx.x;
  const int colBase = blockIdx.x * 128;
  const int rowBase = blockIdx.y * 128;
  const float* Aptr = (rowBase < NROWS) ? (z1 + (size_t)rowBase * DDIM)
                                        : (z2 + (size_t)(rowBase - NROWS) * DDIM);
  const int wv = tid >> 6, ln = tid & 63;
  const int wm = wv & 1, wn = wv >> 1;
  const int lrow = ln & 15, quad = ln >> 4;

  f32x4 acc[4][4] = {};

  for (int k0 = 0; k0 < DDIM; k0 += 32) {
    // stage A (fp32 -> normalized bf16): 128 rows x 32 k
    #pragma unroll
    for (int i = 0; i < 4; i++) {
      int idx = i * 256 + tid;            // 0..1023
      int r = idx >> 3;                   // 0..127
      int kk = (idx & 7) * 4;             // 0..28
      float4 v = *(const float4*)(Aptr + (size_t)r * DDIM + k0 + kk);
      float rn = rnorm[rowBase + r];
      ushort4 o = make_ushort4(f2bf(v.x*rn), f2bf(v.y*rn), f2bf(v.z*rn), f2bf(v.w*rn));
      *(ushort4*)(&As[r * LDT + kk]) = o;
    }
    // stage B (bf16 weight): 128 rows x 32 k
    #pragma unroll
    for (int i = 0; i < 2; i++) {
      int idx = i * 256 + tid;            // 0..511
      int r = idx >> 2;                   // 0..127
      int kk = (idx & 3) * 8;             // 0..24
      float4 v = *(const float4*)(wnb + (size_t)(colBase + r) * DDIM + k0 + kk);
      *(float4*)(&Bs[r * LDT + kk]) = v;
    }
    __syncthreads();
    bf16x8 af[4], bfr[4];
    #pragma unroll
    for (int mi = 0; mi < 4; mi++)
      af[mi] = *(const bf16x8*)(&As[(64*wm + 16*mi + lrow) * LDT + quad*8]);
    #pragma unroll
    for (int ni = 0; ni < 4; ni++)
      bfr[ni] = *(const bf16x8*)(&Bs[(64*wn + 16*ni + lrow) * LDT + quad*8]);
    #pragma unroll
    for (int mi = 0; mi < 4; mi++)
      #pragma unroll
      for (int ni = 0; ni < 4; ni++)
        acc[mi][ni] = __builtin_amdgcn_mfma_f32_16x16x32_bf16(
            af[mi], bfr[ni], acc[mi][ni], 0, 0, 0);
    __syncthreads();
  }
  // epilogue: C/D layout col=lane&15, row=(lane>>4)*4+reg
  #pragma unroll
  for (int mi = 0; mi < 4; mi++)
    #pragma unroll
    for (int ni = 0; ni < 4; ni++)
      #pragma unroll
      for (int r = 0; r < 4; r++) {
        size_t grow = (size_t)rowBase + 64*wm + 16*mi + quad*4 + r;
        int gcol = colBase + 64*wn + 16*ni + lrow;
        zc[grow * KDIM + gcol] = f2bf(acc[mi][ni][r]);
      }
}

// ---------------------------------------------------------------------------
// inline grid barrier: no function calls, so live VGPRs survive.
// bar[0]=arrival count, bar[1]=generation. Requires co-resident grid
// (cooperative launch). Only thread 0 spins; rest wait at __syncthreads.
// ---------------------------------------------------------------------------
__device__ __forceinline__ void grid_barrier(unsigned int* bar, unsigned int nblk) {
  __syncthreads();           // drains each thread's vmcnt (atomics retired)
  if (threadIdx.x == 0) {
    unsigned int gen = __hip_atomic_load(bar + 1, __ATOMIC_RELAXED, __HIP_MEMORY_SCOPE_AGENT);
    unsigned int arrived = __hip_atomic_fetch_add(bar, 1u, __ATOMIC_ACQ_REL, __HIP_MEMORY_SCOPE_AGENT);
    if (arrived == nblk - 1u) {
      __hip_atomic_store(bar, 0u, __ATOMIC_RELAXED, __HIP_MEMORY_SCOPE_AGENT);
      __hip_atomic_store(bar + 1, gen + 1u, __ATOMIC_RELEASE, __HIP_MEMORY_SCOPE_AGENT);
    } else {
      while (__hip_atomic_load(bar + 1, __ATOMIC_ACQUIRE, __HIP_MEMORY_SCOPE_AGENT) == gen)
        __builtin_amdgcn_s_sleep(1);
    }
  }
  __syncthreads();
}

// ---------------------------------------------------------------------------
// sink_coop: all 20 sinkhorn iterations in one cooperative kernel.
// e = exp(20*zc) lives in VGPRs packed as bf16 pairs: 16 rows x 8 cols/lane
// = 64 uint VGPRs data. 256 blocks x 1024 thr = 1 block/CU (co-resident),
// __launch_bounds__(1024,4) -> 128-VGPR cap, ~105 used, no spill.
// blocks 0..127 -> matrix 0 (zc1), 128..255 -> matrix 1 (zc2)
// ---------------------------------------------------------------------------
__global__ __launch_bounds__(1024, 4) void sink_coop(
    const unsigned short* __restrict__ zc, float* __restrict__ T,
    unsigned int* __restrict__ bar) {
  __shared__ float red[16 * 512];
  const int tid = threadIdx.x;
  const int wv = tid >> 6, ln = tid & 63;
  const int gw = blockIdx.x * 16 + wv;      // 0..4095
  const size_t row0 = (size_t)gw * 16;
  const int mat = blockIdx.x >> 7;          // 0 or 1 (block-uniform)

  unsigned int pk[16][4];                    // e packed bf16 pairs
  {
    const unsigned short* base = zc + row0 * 512 + ln * 8;
    #pragma unroll
    for (int r = 0; r < 16; r++) {
      const ushort4* p = (const ushort4*)(base + (size_t)r * 512);
      ushort4 u0 = p[0], u1 = p[1];
      float e0 = __expf(b2f(u0.x)*20.f), e1 = __expf(b2f(u0.y)*20.f);
      float e2 = __expf(b2f(u0.z)*20.f), e3 = __expf(b2f(u0.w)*20.f);
      float e4 = __expf(b2f(u1.x)*20.f), e5 = __expf(b2f(u1.y)*20.f);
      float e6 = __expf(b2f(u1.z)*20.f), e7 = __expf(b2f(u1.w)*20.f);
      pk[r][0] = ((unsigned int)f2bf(e1) << 16) | f2bf(e0);
      pk[r][1] = ((unsigned int)f2bf(e3) << 16) | f2bf(e2);
      pk[r][2] = ((unsigned int)f2bf(e5) << 16) | f2bf(e4);
      pk[r][3] = ((unsigned int)f2bf(e7) << 16) | f2bf(e6);
    }
  }

  for (int t = 0; t < 20; t++) {
    float acc[8] = {0,0,0,0,0,0,0,0};
    if (t == 0) {
      #pragma unroll
      for (int r = 0; r < 16; r++) {
        #pragma unroll
        for (int i = 0; i < 4; i++) {
          acc[2*i]   += __uint_as_float(pk[r][i] << 16);
          acc[2*i+1] += __uint_as_float(pk[r][i] & 0xFFFF0000u);
        }
      }
    } else {
      float a[8];
      const float* Tp = T + (size_t)(t - 1) * 1024 + mat * 512 + ln * 8;
      #pragma unroll
      for (int j = 0; j < 8; j++) {
        float u = __hip_atomic_load(Tp + j, __ATOMIC_RELAXED, __HIP_MEMORY_SCOPE_AGENT);
        a[j] = 1.0f / (512.0f * u);
      }
      #pragma unroll
      for (int r = 0; r < 16; r++) {
        float ev[8];
        #pragma unroll
        for (int i = 0; i < 4; i++) {
          ev[2*i]   = __uint_as_float(pk[r][i] << 16);
          ev[2*i+1] = __uint_as_float(pk[r][i] & 0xFFFF0000u);
        }
        float part = ev[0]*a[0]+ev[1]*a[1]+ev[2]*a[2]+ev[3]*a[3]
                   + ev[4]*a[4]+ev[5]*a[5]+ev[6]*a[6]+ev[7]*a[7];
        #pragma unroll
        for (int off = 1; off < 64; off <<= 1) part += __shfl_xor(part, off);
        float b = 1.0f / (32768.0f * part);
        #pragma unroll
        for (int j = 0; j < 8; j++) acc[j] += ev[j] * b;
      }
    }
    // block reduce: bank-swizzled scalar stores (<=2-way, free), then 512-wide sum
    #pragma unroll
    for (int j = 0; j < 8; j++) {
      int pos = ln * 8 + ((j + (ln >> 2)) & 7);
      red[wv * 512 + pos] = acc[j];
    }
    __syncthreads();
    if (tid < 512) {
      int pos = (tid & ~7) | (((tid & 7) + (tid >> 5)) & 7);
      float s = 0.f;
      #pragma unroll
      for (int w = 0; w < 16; w++) s += red[w * 512 + pos];
      unsafeAtomicAdd(&T[(size_t)t * 1024 + mat * 512 + tid], s);
    }
    grid_barrier(bar, 256u);
  }
}

// ---------------------------------------------------------------------------
// loss: a20 = 1/(K*T19); per row: q = M*a/s (s = sum_k M*a);
// logp = z/tau - logsumexp(z/tau);  out -= (sum_k q1*logp2 + q2*logp1)/N
// 16 waves/block, 4 rows/wave, 512 blocks
// ---------------------------------------------------------------------------
__global__ __launch_bounds__(1024) void loss_kernel(
    const unsigned short* __restrict__ zc,
    const float* __restrict__ T19, float* __restrict__ out) {
  const int tid = threadIdx.x;
  const int wv = tid >> 6, ln = tid & 63;
  const int gw = blockIdx.x * 16 + wv;      // 0..8191
  const size_t row0 = (size_t)gw * 4;
  float a1[8], a2[8];
  #pragma unroll
  for (int j = 0; j < 8; j++) {
    a1[j] = 1.0f / (512.0f * T19[ln*8 + j]);
    a2[j] = 1.0f / (512.0f * T19[512 + ln*8 + j]);
  }
  const float invTau = 1.0f / 0.3f;
  float part = 0.f;
  for (int r = 0; r < 4; r++) {
    size_t b = row0 + r;
    const ushort4* p1 = (const ushort4*)(zc + b * 512 + ln * 8);
    const ushort4* p2 = (const ushort4*)(zc + (b + NROWS) * 512 + ln * 8);
    ushort4 u10 = p1[0], u11 = p1[1], u20 = p2[0], u21 = p2[1];
    float zf1[8], zf2[8];
    zf1[0]=b2f(u10.x); zf1[1]=b2f(u10.y); zf1[2]=b2f(u10.z); zf1[3]=b2f(u10.w);
    zf1[4]=b2f(u11.x); zf1[5]=b2f(u11.y); zf1[6]=b2f(u11.z); zf1[7]=b2f(u11.w);
    zf2[0]=b2f(u20.x); zf2[1]=b2f(u20.y); zf2[2]=b2f(u20.z); zf2[3]=b2f(u20.w);
    zf2[4]=b2f(u21.x); zf2[5]=b2f(u21.y); zf2[6]=b2f(u21.z); zf2[7]=b2f(u21.w);
    float m1 = -1e30f, m2 = -1e30f;
    #pragma unroll
    for (int j = 0; j < 8; j++) { m1 = fmaxf(m1, zf1[j]); m2 = fmaxf(m2, zf2[j]); }
    #pragma unroll
    for (int off = 1; off < 64; off <<= 1) {
      m1 = fmaxf(m1, __shfl_xor(m1, off));
      m2 = fmaxf(m2, __shfl_xor(m2, off));
    }
    float se1 = 0.f, se2 = 0.f;
    #pragma unroll
    for (int j = 0; j < 8; j++) {
      se1 += __expf((zf1[j] - m1) * invTau);
      se2 += __expf((zf2[j] - m2) * invTau);
    }
    #pragma unroll
    for (int off = 1; off < 64; off <<= 1) {
      se1 += __shfl_xor(se1, off);
      se2 += __shfl_xor(se2, off);
    }
    float ls1 = m1 * invTau + __logf(se1);
    float ls2 = m2 * invTau + __logf(se2);
    float s1 = 0.f, n1 = 0.f, s2 = 0.f, n2 = 0.f;
    #pragma unroll
    for (int j = 0; j < 8; j++) {
      float e1 = __expf(zf1[j] * 20.f) * a1[j];
      s1 += e1; n1 += e1 * (zf2[j] * invTau - ls2);
      float e2 = __expf(zf2[j] * 20.f) * a2[j];
      s2 += e2; n2 += e2 * (zf1[j] * invTau - ls1);
    }
    #pragma unroll
    for (int off = 1; off < 64; off <<= 1) {
      s1 += __shfl_xor(s1, off); n1 += __shfl_xor(n1, off);
      s2 += __shfl_xor(s2, off); n2 += __shfl_xor(n2, off);
    }
    part += n1 / s1 + n2 / s2;
  }
  __shared__ float red[16];
  if (ln == 0) red[wv] = part;
  __syncthreads();
  if (tid == 0) {
    float s = 0.f;
    #pragma unroll
    for (int w = 0; w < 16; w++) s += red[w];
    unsafeAtomicAdd(out, -s * (1.0f / 32768.0f));
  }
}

// ---------------------------------------------------------------------------
extern "C" void kernel_launch(void* const* d_in, const int* in_sizes, int n_in,
                              void* d_out, int out_size, void* d_ws, size_t ws_size,
                              hipStream_t stream) {
  (void)in_sizes; (void)n_in; (void)out_size; (void)ws_size;
  const float* z1 = (const float*)d_in[0];
  const float* z2 = (const float*)d_in[1];
  const float* w  = (const float*)d_in[2];
  float* out = (float*)d_out;
  char* ws = (char*)d_ws;
  // workspace layout
  unsigned short* zc    = (unsigned short*)ws;                         // 67,108,864 B
  float*          rnorm = (float*)(ws + (size_t)67108864);             //    262,144 B
  unsigned short* wnb   = (unsigned short*)(ws + (size_t)67371008);    //    524,288 B
  float*          T     = (float*)(ws + (size_t)67895296);             //     81,920 B
  unsigned int*   bar   = (unsigned int*)(T + 20 * 1024);              //          8 B

  hipLaunchKernelGGL(prep_kernel, dim3(16512), dim3(256), 0, stream, z1, z2, w, rnorm, wnb);
  hipLaunchKernelGGL(initvecs_kernel, dim3(81), dim3(256), 0, stream, T, out);
  hipLaunchKernelGGL(gemm_kernel, dim3(4, 512), dim3(256), 0, stream, z1, z2, rnorm, wnb, zc);
  {
    const unsigned short* zc_c = zc;
    float* T_p = T;
    unsigned int* bar_p = bar;
    void* args[] = { (void*)&zc_c, (void*)&T_p, (void*)&bar_p };
    hipLaunchCooperativeKernel((void*)sink_coop, dim3(256), dim3(1024), args, 0, stream);
  }
  hipLaunchKernelGGL(loss_kernel, dim3(512), dim3(1024), 0, stream, zc, T + 19*1024, out);
}

// Round 6
// 1585.861 us; speedup vs baseline: 1.7704x; 1.0016x over previous
//
#include <hip/hip_runtime.h>
#include <stdint.h>

#define NROWS 32768
#define DDIM  512
#define KDIM  512

__device__ __forceinline__ float b2f(unsigned short u) {
  return __uint_as_float(((unsigned int)u) << 16);
}
__device__ __forceinline__ unsigned short f2bf(float f) {
  unsigned int u = __float_as_uint(f);
  u += 0x7FFFu + ((u >> 16) & 1u);   // round-to-nearest-even
  return (unsigned short)(u >> 16);
}

typedef __attribute__((ext_vector_type(8))) short bf16x8;
typedef __attribute__((ext_vector_type(4))) float f32x4;

// ---------------------------------------------------------------------------
// prep: row inverse-norms for z1/z2 (rows 0..65535) and normalized bf16 weight
// ---------------------------------------------------------------------------
__global__ __launch_bounds__(256) void prep_kernel(
    const float* __restrict__ z1, const float* __restrict__ z2,
    const float* __restrict__ w, float* __restrict__ rnorm,
    unsigned short* __restrict__ wnb) {
  const int tid = threadIdx.x;
  const int wv = tid >> 6, ln = tid & 63;
  const int row = blockIdx.x * 4 + wv;   // 0..66047
  const float* src;
  if (row < NROWS)        src = z1 + (size_t)row * DDIM;
  else if (row < 2*NROWS) src = z2 + (size_t)(row - NROWS) * DDIM;
  else                    src = w  + (size_t)(row - 2*NROWS) * DDIM;
  float4 v0 = ((const float4*)src)[ln*2];
  float4 v1 = ((const float4*)src)[ln*2+1];
  float ss = v0.x*v0.x + v0.y*v0.y + v0.z*v0.z + v0.w*v0.w
           + v1.x*v1.x + v1.y*v1.y + v1.z*v1.z + v1.w*v1.w;
  #pragma unroll
  for (int off = 1; off < 64; off <<= 1) ss += __shfl_xor(ss, off);
  float rn = 1.0f / fmaxf(sqrtf(ss), 1e-12f);
  if (row < 2*NROWS) {
    if (ln == 0) rnorm[row] = rn;
  } else {
    int r = row - 2*NROWS;
    ushort4 o0 = make_ushort4(f2bf(v0.x*rn), f2bf(v0.y*rn), f2bf(v0.z*rn), f2bf(v0.w*rn));
    ushort4 o1 = make_ushort4(f2bf(v1.x*rn), f2bf(v1.y*rn), f2bf(v1.z*rn), f2bf(v1.w*rn));
    ushort4* dst = (ushort4*)(wnb + (size_t)r*DDIM + ln*8);
    dst[0] = o0; dst[1] = o1;
  }
}

// ---------------------------------------------------------------------------
// initvecs: zero the 20 column-sum buffers (T[20][2*512]) + barrier + out
// ---------------------------------------------------------------------------
__global__ void initvecs_kernel(float* __restrict__ T, float* __restrict__ out) {
  int i = blockIdx.x * 256 + threadIdx.x;
  if (i < 20 * 1024 + 2) T[i] = 0.f;     // +2: grid-barrier {count, gen}
  if (i == 0) out[0] = 0.f;
}

// ---------------------------------------------------------------------------
// gemm: zc[r,c] = sum_d (z[r,d]*rnorm[r]) * wnb[c,d]   (bf16 MFMA, A*B^T)
// 128x128 tile, BK=32, 4 waves each 64x64 via 4x4 of 16x16x32 MFMAs
// ---------------------------------------------------------------------------
__global__ __launch_bounds__(256) void gemm_kernel(
    const float* __restrict__ z1, const float* __restrict__ z2,
    const float* __restrict__ rnorm, const unsigned short* __restrict__ wnb,
    unsigned short* __restrict__ zc) {
  constexpr int LDT = 40;   // padded LDS stride (elements): 80B rows, 16B aligned
  __shared__ unsigned short As[128 * LDT];
  __shared__ unsigned short Bs[128 * LDT];
  const int tid = threadIdx.x;
  const int colBase = blockIdx.x * 128;
  const int rowBase = blockIdx.y * 128;
  const float* Aptr = (rowBase < NROWS) ? (z1 + (size_t)rowBase * DDIM)
                                        : (z2 + (size_t)(rowBase - NROWS) * DDIM);
  const int wv = tid >> 6, ln = tid & 63;
  const int wm = wv & 1, wn = wv >> 1;
  const int lrow = ln & 15, quad = ln >> 4;

  f32x4 acc[4][4] = {};

  for (int k0 = 0; k0 < DDIM; k0 += 32) {
    // stage A (fp32 -> normalized bf16): 128 rows x 32 k
    #pragma unroll
    for (int i = 0; i < 4; i++) {
      int idx = i * 256 + tid;            // 0..1023
      int r = idx >> 3;                   // 0..127
      int kk = (idx & 7) * 4;             // 0..28
      float4 v = *(const float4*)(Aptr + (size_t)r * DDIM + k0 + kk);
      float rn = rnorm[rowBase + r];
      ushort4 o = make_ushort4(f2bf(v.x*rn), f2bf(v.y*rn), f2bf(v.z*rn), f2bf(v.w*rn));
      *(ushort4*)(&As[r * LDT + kk]) = o;
    }
    // stage B (bf16 weight): 128 rows x 32 k
    #pragma unroll
    for (int i = 0; i < 2; i++) {
      int idx = i * 256 + tid;            // 0..511
      int r = idx >> 2;                   // 0..127
      int kk = (idx & 3) * 8;             // 0..24
      float4 v = *(const float4*)(wnb + (size_t)(colBase + r) * DDIM + k0 + kk);
      *(float4*)(&Bs[r * LDT + kk]) = v;
    }
    __syncthreads();
    bf16x8 af[4], bfr[4];
    #pragma unroll
    for (int mi = 0; mi < 4; mi++)
      af[mi] = *(const bf16x8*)(&As[(64*wm + 16*mi + lrow) * LDT + quad*8]);
    #pragma unroll
    for (int ni = 0; ni < 4; ni++)
      bfr[ni] = *(const bf16x8*)(&Bs[(64*wn + 16*ni + lrow) * LDT + quad*8]);
    #pragma unroll
    for (int mi = 0; mi < 4; mi++)
      #pragma unroll
      for (int ni = 0; ni < 4; ni++)
        acc[mi][ni] = __builtin_amdgcn_mfma_f32_16x16x32_bf16(
            af[mi], bfr[ni], acc[mi][ni], 0, 0, 0);
    __syncthreads();
  }
  // epilogue: C/D layout col=lane&15, row=(lane>>4)*4+reg
  #pragma unroll
  for (int mi = 0; mi < 4; mi++)
    #pragma unroll
    for (int ni = 0; ni < 4; ni++)
      #pragma unroll
      for (int r = 0; r < 4; r++) {
        size_t grow = (size_t)rowBase + 64*wm + 16*mi + quad*4 + r;
        int gcol = colBase + 64*wn + 16*ni + lrow;
        zc[grow * KDIM + gcol] = f2bf(acc[mi][ni][r]);
      }
}

// ---------------------------------------------------------------------------
// inline grid barrier: no function calls, so live VGPRs survive.
// bar[0]=arrival count, bar[1]=generation. Requires co-resident grid
// (cooperative launch). Only thread 0 spins; rest wait at __syncthreads.
// ---------------------------------------------------------------------------
__device__ __forceinline__ void grid_barrier(unsigned int* bar, unsigned int nblk) {
  __syncthreads();           // drains each thread's vmcnt (atomics retired)
  if (threadIdx.x == 0) {
    unsigned int gen = __hip_atomic_load(bar + 1, __ATOMIC_RELAXED, __HIP_MEMORY_SCOPE_AGENT);
    unsigned int arrived = __hip_atomic_fetch_add(bar, 1u, __ATOMIC_ACQ_REL, __HIP_MEMORY_SCOPE_AGENT);
    if (arrived == nblk - 1u) {
      __hip_atomic_store(bar, 0u, __ATOMIC_RELAXED, __HIP_MEMORY_SCOPE_AGENT);
      __hip_atomic_store(bar + 1, gen + 1u, __ATOMIC_RELEASE, __HIP_MEMORY_SCOPE_AGENT);
    } else {
      while (__hip_atomic_load(bar + 1, __ATOMIC_ACQUIRE, __HIP_MEMORY_SCOPE_AGENT) == gen)
        __builtin_amdgcn_s_sleep(1);
    }
  }
  __syncthreads();
}

// ---------------------------------------------------------------------------
// sink_coop: all 20 sinkhorn iterations in one cooperative kernel.
// e = exp(20*zc) lives in VGPRs packed as bf16 pairs: 16 rows x 8 cols/lane
// = 64 uint VGPRs data. 256 blocks x 1024 thr = 1 block/CU (co-resident).
// __launch_bounds__(1024, 1): the 1024-thr workgroup feasibility constraint
// (4 waves/SIMD co-resident) caps VGPRs at 128; (1024,4)/(1024,8) empirically
// clamped the cap to 64 and spilled pk to scratch (rounds 4/5: 1.5 GB FETCH).
// blocks 0..127 -> matrix 0 (zc1), 128..255 -> matrix 1 (zc2)
// ---------------------------------------------------------------------------
__global__ __launch_bounds__(1024, 1) void sink_coop(
    const unsigned short* __restrict__ zc, float* __restrict__ T,
    unsigned int* __restrict__ bar) {
  __shared__ float red[16 * 512];
  const int tid = threadIdx.x;
  const int wv = tid >> 6, ln = tid & 63;
  const int gw = blockIdx.x * 16 + wv;      // 0..4095
  const size_t row0 = (size_t)gw * 16;
  const int mat = blockIdx.x >> 7;          // 0 or 1 (block-uniform)

  unsigned int pk[16][4];                    // e packed bf16 pairs
  {
    const unsigned short* base = zc + row0 * 512 + ln * 8;
    #pragma unroll
    for (int r = 0; r < 16; r++) {
      const ushort4* p = (const ushort4*)(base + (size_t)r * 512);
      ushort4 u0 = p[0], u1 = p[1];
      float e0 = __expf(b2f(u0.x)*20.f), e1 = __expf(b2f(u0.y)*20.f);
      float e2 = __expf(b2f(u0.z)*20.f), e3 = __expf(b2f(u0.w)*20.f);
      float e4 = __expf(b2f(u1.x)*20.f), e5 = __expf(b2f(u1.y)*20.f);
      float e6 = __expf(b2f(u1.z)*20.f), e7 = __expf(b2f(u1.w)*20.f);
      pk[r][0] = ((unsigned int)f2bf(e1) << 16) | f2bf(e0);
      pk[r][1] = ((unsigned int)f2bf(e3) << 16) | f2bf(e2);
      pk[r][2] = ((unsigned int)f2bf(e5) << 16) | f2bf(e4);
      pk[r][3] = ((unsigned int)f2bf(e7) << 16) | f2bf(e6);
    }
  }

  for (int t = 0; t < 20; t++) {
    float acc[8] = {0,0,0,0,0,0,0,0};
    if (t == 0) {
      #pragma unroll
      for (int r = 0; r < 16; r++) {
        #pragma unroll
        for (int i = 0; i < 4; i++) {
          acc[2*i]   += __uint_as_float(pk[r][i] << 16);
          acc[2*i+1] += __uint_as_float(pk[r][i] & 0xFFFF0000u);
        }
      }
    } else {
      float a[8];
      const float* Tp = T + (size_t)(t - 1) * 1024 + mat * 512 + ln * 8;
      #pragma unroll
      for (int j = 0; j < 8; j++) {
        float u = __hip_atomic_load(Tp + j, __ATOMIC_RELAXED, __HIP_MEMORY_SCOPE_AGENT);
        a[j] = 1.0f / (512.0f * u);
      }
      #pragma unroll
      for (int r = 0; r < 16; r++) {
        float ev[8];
        #pragma unroll
        for (int i = 0; i < 4; i++) {
          ev[2*i]   = __uint_as_float(pk[r][i] << 16);
          ev[2*i+1] = __uint_as_float(pk[r][i] & 0xFFFF0000u);
        }
        float part = ev[0]*a[0]+ev[1]*a[1]+ev[2]*a[2]+ev[3]*a[3]
                   + ev[4]*a[4]+ev[5]*a[5]+ev[6]*a[6]+ev[7]*a[7];
        #pragma unroll
        for (int off = 1; off < 64; off <<= 1) part += __shfl_xor(part, off);
        float b = 1.0f / (32768.0f * part);
        #pragma unroll
        for (int j = 0; j < 8; j++) acc[j] += ev[j] * b;
      }
    }
    // block reduce: bank-swizzled scalar stores (<=2-way, free), then 512-wide sum
    #pragma unroll
    for (int j = 0; j < 8; j++) {
      int pos = ln * 8 + ((j + (ln >> 2)) & 7);
      red[wv * 512 + pos] = acc[j];
    }
    __syncthreads();
    if (tid < 512) {
      int pos = (tid & ~7) | (((tid & 7) + (tid >> 5)) & 7);
      float s = 0.f;
      #pragma unroll
      for (int w = 0; w < 16; w++) s += red[w * 512 + pos];
      unsafeAtomicAdd(&T[(size_t)t * 1024 + mat * 512 + tid], s);
    }
    grid_barrier(bar, 256u);
  }
}

// ---------------------------------------------------------------------------
// loss: a20 = 1/(K*T19); per row: q = M*a/s (s = sum_k M*a);
// logp = z/tau - logsumexp(z/tau);  out -= (sum_k q1*logp2 + q2*logp1)/N
// 16 waves/block, 4 rows/wave, 512 blocks
// ---------------------------------------------------------------------------
__global__ __launch_bounds__(1024) void loss_kernel(
    const unsigned short* __restrict__ zc,
    const float* __restrict__ T19, float* __restrict__ out) {
  const int tid = threadIdx.x;
  const int wv = tid >> 6, ln = tid & 63;
  const int gw = blockIdx.x * 16 + wv;      // 0..8191
  const size_t row0 = (size_t)gw * 4;
  float a1[8], a2[8];
  #pragma unroll
  for (int j = 0; j < 8; j++) {
    a1[j] = 1.0f / (512.0f * T19[ln*8 + j]);
    a2[j] = 1.0f / (512.0f * T19[512 + ln*8 + j]);
  }
  const float invTau = 1.0f / 0.3f;
  float part = 0.f;
  for (int r = 0; r < 4; r++) {
    size_t b = row0 + r;
    const ushort4* p1 = (const ushort4*)(zc + b * 512 + ln * 8);
    const ushort4* p2 = (const ushort4*)(zc + (b + NROWS) * 512 + ln * 8);
    ushort4 u10 = p1[0], u11 = p1[1], u20 = p2[0], u21 = p2[1];
    float zf1[8], zf2[8];
    zf1[0]=b2f(u10.x); zf1[1]=b2f(u10.y); zf1[2]=b2f(u10.z); zf1[3]=b2f(u10.w);
    zf1[4]=b2f(u11.x); zf1[5]=b2f(u11.y); zf1[6]=b2f(u11.z); zf1[7]=b2f(u11.w);
    zf2[0]=b2f(u20.x); zf2[1]=b2f(u20.y); zf2[2]=b2f(u20.z); zf2[3]=b2f(u20.w);
    zf2[4]=b2f(u21.x); zf2[5]=b2f(u21.y); zf2[6]=b2f(u21.z); zf2[7]=b2f(u21.w);
    float m1 = -1e30f, m2 = -1e30f;
    #pragma unroll
    for (int j = 0; j < 8; j++) { m1 = fmaxf(m1, zf1[j]); m2 = fmaxf(m2, zf2[j]); }
    #pragma unroll
    for (int off = 1; off < 64; off <<= 1) {
      m1 = fmaxf(m1, __shfl_xor(m1, off));
      m2 = fmaxf(m2, __shfl_xor(m2, off));
    }
    float se1 = 0.f, se2 = 0.f;
    #pragma unroll
    for (int j = 0; j < 8; j++) {
      se1 += __expf((zf1[j] - m1) * invTau);
      se2 += __expf((zf2[j] - m2) * invTau);
    }
    #pragma unroll
    for (int off = 1; off < 64; off <<= 1) {
      se1 += __shfl_xor(se1, off);
      se2 += __shfl_xor(se2, off);
    }
    float ls1 = m1 * invTau + __logf(se1);
    float ls2 = m2 * invTau + __logf(se2);
    float s1 = 0.f, n1 = 0.f, s2 = 0.f, n2 = 0.f;
    #pragma unroll
    for (int j = 0; j < 8; j++) {
      float e1 = __expf(zf1[j] * 20.f) * a1[j];
      s1 += e1; n1 += e1 * (zf2[j] * invTau - ls2);
      float e2 = __expf(zf2[j] * 20.f) * a2[j];
      s2 += e2; n2 += e2 * (zf1[j] * invTau - ls1);
    }
    #pragma unroll
    for (int off = 1; off < 64; off <<= 1) {
      s1 += __shfl_xor(s1, off); n1 += __shfl_xor(n1, off);
      s2 += __shfl_xor(s2, off); n2 += __shfl_xor(n2, off);
    }
    part += n1 / s1 + n2 / s2;
  }
  __shared__ float red[16];
  if (ln == 0) red[wv] = part;
  __syncthreads();
  if (tid == 0) {
    float s = 0.f;
    #pragma unroll
    for (int w = 0; w < 16; w++) s += red[w];
    unsafeAtomicAdd(out, -s * (1.0f / 32768.0f));
  }
}

// ---------------------------------------------------------------------------
extern "C" void kernel_launch(void* const* d_in, const int* in_sizes, int n_in,
                              void* d_out, int out_size, void* d_ws, size_t ws_size,
                              hipStream_t stream) {
  (void)in_sizes; (void)n_in; (void)out_size; (void)ws_size;
  const float* z1 = (const float*)d_in[0];
  const float* z2 = (const float*)d_in[1];
  const float* w  = (const float*)d_in[2];
  float* out = (float*)d_out;
  char* ws = (char*)d_ws;
  // workspace layout
  unsigned short* zc    = (unsigned short*)ws;                         // 67,108,864 B
  float*          rnorm = (float*)(ws + (size_t)67108864);             //    262,144 B
  unsigned short* wnb   = (unsigned short*)(ws + (size_t)67371008);    //    524,288 B
  float*          T     = (float*)(ws + (size_t)67895296);             //     81,920 B
  unsigned int*   bar   = (unsigned int*)(T + 20 * 1024);              //          8 B

  hipLaunchKernelGGL(prep_kernel, dim3(16512), dim3(256), 0, stream, z1, z2, w, rnorm, wnb);
  hipLaunchKernelGGL(initvecs_kernel, dim3(81), dim3(256), 0, stream, T, out);
  hipLaunchKernelGGL(gemm_kernel, dim3(4, 512), dim3(256), 0, stream, z1, z2, rnorm, wnb, zc);
  {
    const unsigned short* zc_c = zc;
    float* T_p = T;
    unsigned int* bar_p = bar;
    void* args[] = { (void*)&zc_c, (void*)&T_p, (void*)&bar_p };
    hipLaunchCooperativeKernel((void*)sink_coop, dim3(256), dim3(1024), args, 0, stream);
  }
  hipLaunchKernelGGL(loss_kernel, dim3(512), dim3(1024), 0, stream, zc, T + 19*1024, out);
}